// Round 6
// baseline (219.053 us; speedup 1.0000x reference)
//
#include <hip/hip_runtime.h>
#include <hip/hip_bf16.h>

typedef __attribute__((ext_vector_type(8))) short short8;
typedef __attribute__((ext_vector_type(4))) float f32x4;
typedef __attribute__((ext_vector_type(4))) unsigned short u16x4;
typedef __attribute__((ext_vector_type(4))) int int4v;
typedef __attribute__((ext_vector_type(2))) unsigned int u32x2;

#define DEVI static __device__ __forceinline__

constexpr int B_ = 4, S_ = 2048, D_ = 768, NH_ = 12, DH_ = 64;
constexpr int M_ = B_ * S_;                 // 8192
constexpr size_t NX = (size_t)M_ * D_;      // 6291456 elems
constexpr size_t NW = (size_t)D_ * D_;      // 589824 elems

DEVI unsigned short f2bf(float f) {
  union { float f; unsigned u; } c; c.f = f;
  unsigned u = c.u;
  return (unsigned short)((u + 0x7FFFu + ((u >> 16) & 1u)) >> 16);  // RNE
}

DEVI unsigned cvtpk_bf16(float lo, float hi) {
  unsigned r;
  asm("v_cvt_pk_bf16_f32 %0, %1, %2" : "=v"(r) : "v"(lo), "v"(hi));
  return r;  // low16 = bf16(lo), high16 = bf16(hi)
}

DEVI void gload16(const void* g, void* l) {
  __builtin_amdgcn_global_load_lds(
      (const __attribute__((address_space(1))) void*)g,
      (__attribute__((address_space(3))) void*)l, 16, 0, 0);
}

// ---------------------------------------------------------------- convert
// 1D packed grid: [0,18432) X segs, [18432,20736) W combined, [20736,20744) mask
__global__ __launch_bounds__(256) void convert_kernel(
    const float* __restrict__ q, const float* __restrict__ k,
    const float* __restrict__ v, const float* __restrict__ qw_,
    const float* __restrict__ kw_, const float* __restrict__ vw_,
    const float* __restrict__ ow_, const int* __restrict__ smask,
    unsigned short* __restrict__ Xq, unsigned short* __restrict__ Xk,
    unsigned short* __restrict__ Xv, unsigned short* __restrict__ Wc,
    float* __restrict__ dmask) {
  const long bid = blockIdx.x;
  const int tid = threadIdx.x;
  if (bid < 18432) {
    const int seg = (int)(bid / 6144);
    const long i = (bid % 6144) * 256 + tid;
    const float* src = seg == 0 ? q : seg == 1 ? k : v;
    unsigned short* dst = seg == 0 ? Xq : seg == 1 ? Xk : Xv;
    f32x4 vv = *(const f32x4*)(src + i * 4);
    u16x4 o;
    o.x = f2bf(vv.x); o.y = f2bf(vv.y); o.z = f2bf(vv.z); o.w = f2bf(vv.w);
    *(u16x4*)(dst + i * 4) = o;
  } else if (bid < 20736) {
    const long e = ((bid - 18432) * 256 + tid) * 4;  // elem in [0, 4*NW)
    const int j = (int)(e / (long)NW);
    const float* src = j == 0 ? qw_ : j == 1 ? kw_ : j == 2 ? vw_ : ow_;
    f32x4 vv = *(const f32x4*)(src + (e - (long)j * NW));
    u16x4 o;
    o.x = f2bf(vv.x); o.y = f2bf(vv.y); o.z = f2bf(vv.z); o.w = f2bf(vv.w);
    *(u16x4*)(Wc + e) = o;
  } else {
    const long i = (bid - 20736) * 256 + tid;
    int4v m = *(const int4v*)(smask + i * 4);
    f32x4 o;
    o.x = m.x ? 0.f : -1e30f; o.y = m.y ? 0.f : -1e30f;
    o.z = m.z ? 0.f : -1e30f; o.w = m.w ? 0.f : -1e30f;
    *(f32x4*)(dmask + i * 4) = o;
  }
}

// ---------------------------------------------------------------- gemm core
// C[128x128] tile of A[M,768] @ Bt[768,768]^T, bf16 MFMA 16x16x32.
// 4 waves, each 64x64 (4x4 frags). BK=32, DOUBLE-BUFFERED global_load_lds:
// stage(k+1) issued before compute(k), ONE barrier per k-step (T3 minimum).
DEVI void gemm_core(const unsigned short* __restrict__ A,
                    const unsigned short* __restrict__ Bt,
                    unsigned short* As, unsigned short* Bs,
                    int m0, int n0, int tid, f32x4 acc[4][4]) {
  const int w = tid >> 6, l = tid & 63;
  const int wm = w >> 1, wn = w & 1;
  const int lr = l & 15, lg = l >> 4;

  const unsigned short* gA0 = A  + (size_t)(m0 + (tid >> 2)) * 768 + (tid & 3) * 8;
  const unsigned short* gB0 = Bt + (size_t)(n0 + (tid >> 2)) * 768 + (tid & 3) * 8;
  const int wslot = w * 512;  // wave-uniform LDS base (64 rows x 8 halves)

  // prologue: stage k=0 into buffer 0
  gload16(gA0, As + wslot);
  gload16(gA0 + (size_t)64 * 768, As + wslot + 2048);
  gload16(gB0, Bs + wslot);
  gload16(gB0 + (size_t)64 * 768, Bs + wslot + 2048);
  __syncthreads();

  int buf = 0;
  for (int k0 = 0; k0 < 768; k0 += 32) {
    // stage NEXT k-tile into the other buffer (drains at end-of-iter barrier)
    if (k0 + 32 < 768) {
      const int nb = (buf ^ 1) * 4096;
      gload16(gA0 + k0 + 32, As + nb + wslot);
      gload16(gA0 + (size_t)64 * 768 + k0 + 32, As + nb + wslot + 2048);
      gload16(gB0 + k0 + 32, Bs + nb + wslot);
      gload16(gB0 + (size_t)64 * 768 + k0 + 32, Bs + nb + wslot + 2048);
    }
    const unsigned short* fA = As + buf * 4096 + (size_t)(wm * 64 + lr) * 32 + lg * 8;
    const unsigned short* fB = Bs + buf * 4096 + (size_t)(wn * 64 + lr) * 32 + lg * 8;
    short8 af[4], bf[4];
#pragma unroll
    for (int m = 0; m < 4; m++) af[m] = *(const short8*)(fA + m * 16 * 32);
#pragma unroll
    for (int n = 0; n < 4; n++) bf[n] = *(const short8*)(fB + n * 16 * 32);
    __builtin_amdgcn_s_setprio(1);
#pragma unroll
    for (int m = 0; m < 4; m++)
#pragma unroll
      for (int n = 0; n < 4; n++)
        acc[m][n] = __builtin_amdgcn_mfma_f32_16x16x32_bf16(af[m], bf[n], acc[m][n], 0, 0, 0);
    __builtin_amdgcn_s_setprio(0);
    __syncthreads();  // drains stage (vmcnt0) + releases read buffer
    buf ^= 1;
  }
}

// ---------------------------------------------------------------- QKV gemm
// z=0: Q (scaled by 0.125*log2e for exp2-domain softmax), z=1: K, z=2: V
// written DIRECTLY transposed to Vt[B,H,D,S] (fused transpose).
__global__ __launch_bounds__(256) void qkv_gemm(
    const unsigned short* __restrict__ Xq, const unsigned short* __restrict__ Xk,
    const unsigned short* __restrict__ Xv,
    const unsigned short* __restrict__ Wq, const unsigned short* __restrict__ Wk,
    const unsigned short* __restrict__ Wv,
    const float* __restrict__ bq, const float* __restrict__ bk,
    const float* __restrict__ bv,
    unsigned short* __restrict__ Oq, unsigned short* __restrict__ Ok,
    unsigned short* __restrict__ Vt) {
  __shared__ unsigned short As[2 * 4096], Bs[2 * 4096];
  const int z = blockIdx.z;
  const unsigned short* A  = (z == 0) ? Xq : (z == 1) ? Xk : Xv;
  const unsigned short* Bt = (z == 0) ? Wq : (z == 1) ? Wk : Wv;
  const float* bias        = (z == 0) ? bq : (z == 1) ? bk : bv;
  // 0.125 * log2(e): QK^T scores land in log2 domain -> exp2 softmax
  const float scale = (z == 0) ? 0.125f * 1.44269504f : 1.0f;

  const int m0 = blockIdx.x * 128, n0 = blockIdx.y * 128;
  f32x4 acc[4][4] = {};
  gemm_core(A, Bt, As, Bs, m0, n0, threadIdx.x, acc);

  const int tid = threadIdx.x, w = tid >> 6, l = tid & 63;
  const int wm = w >> 1, wn = w & 1, lr = l & 15, lg = l >> 4;
  if (z == 2) {
    // fused V transpose: write Vt[((b*NH+h)*DH + d)*S + s]
#pragma unroll
    for (int n = 0; n < 4; n++) {
      const int ng = n0 + wn * 64 + n * 16 + lr;
      const float bvv = bias[ng];
      const int h = ng >> 6, d = ng & 63;
#pragma unroll
      for (int m = 0; m < 4; m++) {
#pragma unroll
        for (int r = 0; r < 4; r++) {
          const int mg = m0 + wm * 64 + m * 16 + lg * 4 + r;
          const int b = mg >> 11, s = mg & 2047;
          Vt[((size_t)(b * NH_ + h) * DH_ + d) * S_ + s] = f2bf(acc[m][n][r] + bvv);
        }
      }
    }
  } else {
    unsigned short* O = (z == 0) ? Oq : Ok;
#pragma unroll
    for (int n = 0; n < 4; n++) {
      const int ng = n0 + wn * 64 + n * 16 + lr;
      const float bvv = bias[ng];
      const int h = ng >> 6, d = ng & 63;
#pragma unroll
      for (int m = 0; m < 4; m++) {
#pragma unroll
        for (int r = 0; r < 4; r++) {
          const int mg = m0 + wm * 64 + m * 16 + lg * 4 + r;
          const int b = mg >> 11, s = mg & 2047;
          O[((size_t)(b * NH_ + h) * S_ + s) * DH_ + d] = f2bf((acc[m][n][r] + bvv) * scale);
        }
      }
    }
  }
}

// ---------------------------------------------------------------- out gemm
__global__ __launch_bounds__(256) void out_gemm(
    const unsigned short* __restrict__ A, const unsigned short* __restrict__ Bt,
    const float* __restrict__ bias, float* __restrict__ out) {
  __shared__ unsigned short As[2 * 4096], Bs[2 * 4096];
  const int m0 = blockIdx.x * 128, n0 = blockIdx.y * 128;
  f32x4 acc[4][4] = {};
  gemm_core(A, Bt, As, Bs, m0, n0, threadIdx.x, acc);

  const int tid = threadIdx.x, w = tid >> 6, l = tid & 63;
  const int wm = w >> 1, wn = w & 1, lr = l & 15, lg = l >> 4;
#pragma unroll
  for (int n = 0; n < 4; n++) {
    const int ng = n0 + wn * 64 + n * 16 + lr;
    const float bvv = bias[ng];
#pragma unroll
    for (int m = 0; m < 4; m++) {
#pragma unroll
      for (int r = 0; r < 4; r++) {
        const int mg = m0 + wm * 64 + m * 16 + lg * 4 + r;
        out[(size_t)mg * 768 + ng] = acc[m][n][r] + bvv;
      }
    }
  }
}

// ---------------------------------------------------------------- attention
// Swapped-QK^T flash attn, LDS-pipelined (T3 minimum 2-phase), exp2-domain
// softmax (log2e folded into Q scale). 4 waves x 32 q = 128 q/block,
// grid 768 (XCD-swizzled, 6 bh/XCD). KV tile = 64 keys double-buffered via
// global_load_lds with pre-swizzled SOURCE (rule #21); reads XOR-deswizzle.
// Ps row stride = 72 shorts: payload is 64 keys (64 shorts) + 8 pad.
__global__ __launch_bounds__(256) void attn_kernel(
    const unsigned short* __restrict__ Qp, const unsigned short* __restrict__ Kp,
    const unsigned short* __restrict__ Vt, const float* __restrict__ maskadd,
    unsigned short* __restrict__ Ctx) {
  __shared__ unsigned short KsA[4096], KsB[4096];  // [key][d] swizzled, 8KB each
  __shared__ unsigned short VsA[4096], VsB[4096];  // [d][key] swizzled
  __shared__ unsigned short Ps[4][16][72];         // per-wave P relayout buffer

  // XCD swizzle: xcd = id & 7 (hw maps blockIdx%8 -> XCD); 6 bh per XCD
  const int id = blockIdx.x;               // 0..767
  const int xcd = id & 7, slot = id >> 3;  // 96 slots
  const int bh = xcd + 8 * (slot >> 4);    // 48 bh
  const int qt = slot & 15;                // 16 q-tiles of 128
  const int b = bh / NH_, h = bh % NH_;
  const int tid = threadIdx.x, w = tid >> 6, l = tid & 63;
  const int lr = l & 15, lg = l >> 4;
  const int rsw = lr & 7;
  const int qw = qt * 128 + w * 32;

  // Q fragments (B-operand of S^T): lane lr = q, k-dim d = lg*8 + ks*32
  short8 aq[2][2];
#pragma unroll
  for (int qb = 0; qb < 2; qb++)
#pragma unroll
    for (int ks = 0; ks < 2; ks++)
      aq[qb][ks] = *(const short8*)&Qp[((size_t)bh * S_ + qw + qb * 16 + lr) * DH_ +
                                       lg * 8 + ks * 32];

  // staging addresses: thread covers LDS 16B-units {tid, tid+256};
  // unit u: row=u>>3, c=u&7; source col unit cg = c ^ (row&7) (involution)
  const int r0 = tid >> 3, c0 = tid & 7;
  const int cg = c0 ^ (r0 & 7);
  const unsigned short* Kg0 = Kp + ((size_t)bh * S_ + r0) * DH_ + cg * 8;
  const unsigned short* Kg1 = Kg0 + (size_t)32 * DH_;
  const unsigned short* Vg0 = Vt + ((size_t)bh * DH_ + r0) * S_ + cg * 8;
  const unsigned short* Vg1 = Vg0 + (size_t)32 * S_;
  const int wslot = w * 512;  // wave-uniform LDS offset

  const float* Mb = maskadd + b * S_ + lg * 4;

  float m_run[2], l_run[2];
  f32x4 ctx[2][4] = {};
#pragma unroll
  for (int qb = 0; qb < 2; qb++) { m_run[qb] = -INFINITY; l_run[qb] = 0.f; }

  unsigned short* Pw = &Ps[w][0][0];
  unsigned* Prow = (unsigned*)(Pw + lr * 72);
  const unsigned short* Prd = Pw + lr * 72 + lg * 8;

  unsigned short *Krd = KsA, *Vrd = VsA, *Kwr = KsB, *Vwr = VsB;

  // prologue: stage tile 0
  gload16(Kg0, KsA + wslot);
  gload16(Kg1, KsA + 2048 + wslot);
  gload16(Vg0, VsA + wslot);
  gload16(Vg1, VsA + 2048 + wslot);
  __syncthreads();

  for (int kt = 0; kt < S_ / 64; kt++) {
    // ---- stage NEXT tile into write buffer (async, drains at end barrier)
    if (kt + 1 < S_ / 64) {
      const size_t ko = (size_t)(kt + 1) * 64 * DH_;
      const int vo = (kt + 1) * 64;
      gload16(Kg0 + ko, Kwr + wslot);
      gload16(Kg1 + ko, Kwr + 2048 + wslot);
      gload16(Vg0 + vo, Vwr + wslot);
      gload16(Vg1 + vo, Vwr + 2048 + wslot);
    }

    // ---- mask addend (L2-hot)
    const int kv0 = kt * 64;
    f32x4 mk[4];
#pragma unroll
    for (int t = 0; t < 4; t++) mk[t] = *(const f32x4*)(Mb + kv0 + 16 * t);

    // ---- S^T = K.Q from LDS (swizzled reads), both q sub-blocks share kf
    f32x4 sacc[2][4] = {};
    __builtin_amdgcn_s_setprio(1);
#pragma unroll
    for (int t = 0; t < 4; t++) {
      const int row = 16 * t + lr;
      short8 kf0 = *(const short8*)&Krd[row * 64 + ((lg) ^ rsw) * 8];
      short8 kf1 = *(const short8*)&Krd[row * 64 + ((lg + 4) ^ rsw) * 8];
      sacc[0][t] = __builtin_amdgcn_mfma_f32_16x16x32_bf16(kf0, aq[0][0], sacc[0][t], 0, 0, 0);
      sacc[0][t] = __builtin_amdgcn_mfma_f32_16x16x32_bf16(kf1, aq[0][1], sacc[0][t], 0, 0, 0);
      sacc[1][t] = __builtin_amdgcn_mfma_f32_16x16x32_bf16(kf0, aq[1][0], sacc[1][t], 0, 0, 0);
      sacc[1][t] = __builtin_amdgcn_mfma_f32_16x16x32_bf16(kf1, aq[1][1], sacc[1][t], 0, 0, 0);
    }
    __builtin_amdgcn_s_setprio(0);

    // ---- softmax (exp2 domain) per q sub-block; P -> per-wave LDS -> pa regs
    short8 pa[2][2];
#pragma unroll
    for (int qb = 0; qb < 2; qb++) {
#pragma unroll
      for (int t = 0; t < 4; t++)
#pragma unroll
        for (int r = 0; r < 4; r++) sacc[qb][t][r] += mk[t][r];

      // max-reduce via v_max3-friendly triples (16 vals -> 8 insts)
      float t0 = fmaxf(fmaxf(sacc[qb][0][0], sacc[qb][0][1]), sacc[qb][0][2]);
      float t1 = fmaxf(fmaxf(sacc[qb][0][3], sacc[qb][1][0]), sacc[qb][1][1]);
      float t2 = fmaxf(fmaxf(sacc[qb][1][2], sacc[qb][1][3]), sacc[qb][2][0]);
      float t3 = fmaxf(fmaxf(sacc[qb][2][1], sacc[qb][2][2]), sacc[qb][2][3]);
      float t4 = fmaxf(fmaxf(sacc[qb][3][0], sacc[qb][3][1]), sacc[qb][3][2]);
      float mx = fmaxf(fmaxf(fmaxf(t0, t1), fmaxf(t2, t3)),
                       fmaxf(t4, sacc[qb][3][3]));
      mx = fmaxf(mx, __shfl_xor(mx, 16));
      mx = fmaxf(mx, __shfl_xor(mx, 32));

      // defer-max (log2 domain: 8 nats ~ 11.5 bits)
      if (!__all(mx <= m_run[qb] + 11.5f)) {
        const float nm = fmaxf(m_run[qb], mx);
        const float al = exp2f(m_run[qb] - nm);
        m_run[qb] = nm;
        l_run[qb] *= al;
        float av[4];
#pragma unroll
        for (int r = 0; r < 4; r++) av[r] = __shfl(al, lg * 4 + r, 16);
#pragma unroll
        for (int dt = 0; dt < 4; dt++)
#pragma unroll
          for (int r = 0; r < 4; r++) ctx[qb][dt][r] *= av[r];
      }

      float ts = 0.f;
#pragma unroll
      for (int t = 0; t < 4; t++)
#pragma unroll
        for (int r = 0; r < 4; r++) {
          const float p = exp2f(sacc[qb][t][r] - m_run[qb]);
          sacc[qb][t][r] = p; ts += p;
        }
      ts += __shfl_xor(ts, 16);
      ts += __shfl_xor(ts, 32);
      l_run[qb] += ts;

      // P -> bf16 (cvt_pk) -> per-wave LDS row -> A-fragment regs
#pragma unroll
      for (int t = 0; t < 4; t++) {
        u32x2 c;
        c.x = cvtpk_bf16(sacc[qb][t][0], sacc[qb][t][1]);
        c.y = cvtpk_bf16(sacc[qb][t][2], sacc[qb][t][3]);
        *(u32x2*)(Prow + 8 * t + lg * 2) = c;
      }
      pa[qb][0] = *(const short8*)(Prd);
      pa[qb][1] = *(const short8*)(Prd + 32);
    }

    // ---- PV: vf read once, shared by both q sub-blocks
    __builtin_amdgcn_s_setprio(1);
#pragma unroll
    for (int dt = 0; dt < 4; dt++) {
      const int row = 16 * dt + lr;
      short8 vf0 = *(const short8*)&Vrd[row * 64 + ((lg) ^ rsw) * 8];
      short8 vf1 = *(const short8*)&Vrd[row * 64 + ((lg + 4) ^ rsw) * 8];
      ctx[0][dt] = __builtin_amdgcn_mfma_f32_16x16x32_bf16(pa[0][0], vf0, ctx[0][dt], 0, 0, 0);
      ctx[0][dt] = __builtin_amdgcn_mfma_f32_16x16x32_bf16(pa[0][1], vf1, ctx[0][dt], 0, 0, 0);
      ctx[1][dt] = __builtin_amdgcn_mfma_f32_16x16x32_bf16(pa[1][0], vf0, ctx[1][dt], 0, 0, 0);
      ctx[1][dt] = __builtin_amdgcn_mfma_f32_16x16x32_bf16(pa[1][1], vf1, ctx[1][dt], 0, 0, 0);
    }
    __builtin_amdgcn_s_setprio(0);

    // ---- single barrier per tile: drains stage (vmcnt0) + protects buffers
    __syncthreads();
    unsigned short* t0p = Krd; Krd = Kwr; Kwr = t0p;
    unsigned short* t1p = Vrd; Vrd = Vwr; Vwr = t1p;
  }

  // ---- epilogue: normalize, write bf16 ctx
#pragma unroll
  for (int qb = 0; qb < 2; qb++) {
    const float linv = 1.f / l_run[qb];
    float iv[4];
#pragma unroll
    for (int r = 0; r < 4; r++) iv[r] = __shfl(linv, lg * 4 + r, 16);
#pragma unroll
    for (int r = 0; r < 4; r++) {
      const int qg = qw + qb * 16 + lg * 4 + r;
#pragma unroll
      for (int dt = 0; dt < 4; dt++) {
        Ctx[((size_t)b * S_ + qg) * D_ + h * DH_ + dt * 16 + lr] =
            f2bf(ctx[qb][dt][r] * iv[r]);
      }
    }
  }
}

// ---------------------------------------------------------------- launcher
extern "C" void kernel_launch(void* const* d_in, const int* in_sizes, int n_in,
                              void* d_out, int out_size, void* d_ws, size_t ws_size,
                              hipStream_t stream) {
  const float* q   = (const float*)d_in[0];
  const float* k   = (const float*)d_in[1];
  const float* v   = (const float*)d_in[2];
  const int* mask  = (const int*)d_in[3];
  const float* q_w = (const float*)d_in[4];
  const float* q_b = (const float*)d_in[5];
  const float* k_w = (const float*)d_in[6];
  const float* k_b = (const float*)d_in[7];
  const float* v_w = (const float*)d_in[8];
  const float* v_b = (const float*)d_in[9];
  const float* o_w = (const float*)d_in[10];
  const float* o_b = (const float*)d_in[11];
  float* out = (float*)d_out;

  unsigned short* ws = (unsigned short*)d_ws;
  unsigned short* Xq = ws;
  unsigned short* Xk = Xq + NX;
  unsigned short* Xv = Xk + NX;
  unsigned short* Wq = Xv + NX;   // Wq..Wo contiguous (convert writes combined)
  unsigned short* Wk = Wq + NW;
  unsigned short* Wv = Wk + NW;
  unsigned short* Wo = Wv + NW;
  unsigned short* Qp = Wo + NW;
  unsigned short* Kp = Qp + NX;
  unsigned short* Vt = Kp + NX;   // V written transposed directly by qkv_gemm
  float* Ma = (float*)(Vt + NX);  // mask addend table, 4x2048 f32
  unsigned short* Ctx = Xq;       // alias: Xq dead after its GEMM

  convert_kernel<<<dim3(20744), dim3(256), 0, stream>>>(
      q, k, v, q_w, k_w, v_w, o_w, mask, Xq, Xk, Xv, Wq, Ma);

  qkv_gemm<<<dim3(64, 6, 3), dim3(256), 0, stream>>>(
      Xq, Xk, Xv, Wq, Wk, Wv, q_b, k_b, v_b, Qp, Kp, Vt);

  attn_kernel<<<dim3(768), dim3(256), 0, stream>>>(Qp, Kp, Vt, Ma, Ctx);

  out_gemm<<<dim3(64, 6), dim3(256), 0, stream>>>(Ctx, Wo, o_b, out);
}

// Round 7
// 200.234 us; speedup vs baseline: 1.0940x; 1.0940x over previous
//
#include <hip/hip_runtime.h>
#include <hip/hip_bf16.h>

typedef __attribute__((ext_vector_type(8))) short short8;
typedef __attribute__((ext_vector_type(4))) float f32x4;
typedef __attribute__((ext_vector_type(4))) unsigned short u16x4;
typedef __attribute__((ext_vector_type(4))) int int4v;
typedef __attribute__((ext_vector_type(2))) unsigned int u32x2;

#define DEVI static __device__ __forceinline__

constexpr int B_ = 4, S_ = 2048, D_ = 768, NH_ = 12, DH_ = 64;
constexpr int M_ = B_ * S_;                 // 8192
constexpr size_t NX = (size_t)M_ * D_;      // 6291456 elems
constexpr size_t NW = (size_t)D_ * D_;      // 589824 elems

DEVI unsigned short f2bf(float f) {
  union { float f; unsigned u; } c; c.f = f;
  unsigned u = c.u;
  return (unsigned short)((u + 0x7FFFu + ((u >> 16) & 1u)) >> 16);  // RNE
}

DEVI unsigned cvtpk_bf16(float lo, float hi) {
  unsigned r;
  asm("v_cvt_pk_bf16_f32 %0, %1, %2" : "=v"(r) : "v"(lo), "v"(hi));
  return r;  // low16 = bf16(lo), high16 = bf16(hi)
}

// 2^x via the hardware transcendental (1 inst). exp2f() is the ACCURATE
// OCML libm routine (denormal fixups + branches) -- R6 regression lesson.
DEVI float fexp2(float x) {
  float r;
  asm("v_exp_f32 %0, %1" : "=v"(r) : "v"(x));
  return r;
}

DEVI void gload16(const void* g, void* l) {
  __builtin_amdgcn_global_load_lds(
      (const __attribute__((address_space(1))) void*)g,
      (__attribute__((address_space(3))) void*)l, 16, 0, 0);
}

// ---------------------------------------------------------------- convert
// 1D packed grid: [0,18432) X segs, [18432,20736) W combined, [20736,20744) mask
__global__ __launch_bounds__(256) void convert_kernel(
    const float* __restrict__ q, const float* __restrict__ k,
    const float* __restrict__ v, const float* __restrict__ qw_,
    const float* __restrict__ kw_, const float* __restrict__ vw_,
    const float* __restrict__ ow_, const int* __restrict__ smask,
    unsigned short* __restrict__ Xq, unsigned short* __restrict__ Xk,
    unsigned short* __restrict__ Xv, unsigned short* __restrict__ Wc,
    float* __restrict__ dmask) {
  const long bid = blockIdx.x;
  const int tid = threadIdx.x;
  if (bid < 18432) {
    const int seg = (int)(bid / 6144);
    const long i = (bid % 6144) * 256 + tid;
    const float* src = seg == 0 ? q : seg == 1 ? k : v;
    unsigned short* dst = seg == 0 ? Xq : seg == 1 ? Xk : Xv;
    f32x4 vv = *(const f32x4*)(src + i * 4);
    u16x4 o;
    o.x = f2bf(vv.x); o.y = f2bf(vv.y); o.z = f2bf(vv.z); o.w = f2bf(vv.w);
    *(u16x4*)(dst + i * 4) = o;
  } else if (bid < 20736) {
    const long e = ((bid - 18432) * 256 + tid) * 4;  // elem in [0, 4*NW)
    const int j = (int)(e / (long)NW);
    const float* src = j == 0 ? qw_ : j == 1 ? kw_ : j == 2 ? vw_ : ow_;
    f32x4 vv = *(const f32x4*)(src + (e - (long)j * NW));
    u16x4 o;
    o.x = f2bf(vv.x); o.y = f2bf(vv.y); o.z = f2bf(vv.z); o.w = f2bf(vv.w);
    *(u16x4*)(Wc + e) = o;
  } else {
    const long i = (bid - 20736) * 256 + tid;
    int4v m = *(const int4v*)(smask + i * 4);
    f32x4 o;
    o.x = m.x ? 0.f : -1e30f; o.y = m.y ? 0.f : -1e30f;
    o.z = m.z ? 0.f : -1e30f; o.w = m.w ? 0.f : -1e30f;
    *(f32x4*)(dmask + i * 4) = o;
  }
}

// ---------------------------------------------------------------- gemm core
// C[128x128] tile of A[M,768] @ Bt[768,768]^T, bf16 MFMA 16x16x32.
// 4 waves, each 64x64 (4x4 frags). BK=32, double-buffered global_load_lds
// with COUNTED vmcnt (T4): stage(k+1) stays in flight across the barrier;
// vmcnt(4) waits only the current tile's 4 loads. Two raw s_barriers/iter.
DEVI void gemm_core(const unsigned short* __restrict__ A,
                    const unsigned short* __restrict__ Bt,
                    unsigned short* As, unsigned short* Bs,
                    int m0, int n0, int tid, f32x4 acc[4][4]) {
  const int w = tid >> 6, l = tid & 63;
  const int wm = w >> 1, wn = w & 1;
  const int lr = l & 15, lg = l >> 4;

  const unsigned short* gA0 = A  + (size_t)(m0 + (tid >> 2)) * 768 + (tid & 3) * 8;
  const unsigned short* gB0 = Bt + (size_t)(n0 + (tid >> 2)) * 768 + (tid & 3) * 8;
  const int wslot = w * 512;  // wave-uniform LDS base (64 rows x 8 halves)

  // prologue: stage k=0 into buffer 0 (4 loads/thread outstanding)
  gload16(gA0, As + wslot);
  gload16(gA0 + (size_t)64 * 768, As + wslot + 2048);
  gload16(gB0, Bs + wslot);
  gload16(gB0 + (size_t)64 * 768, Bs + wslot + 2048);

  int buf = 0;
  for (int k0 = 0; k0 < 768; k0 += 32) {
    // stage NEXT k-tile into the other buffer; keep it in flight (vmcnt(4))
    if (k0 + 32 < 768) {
      const int nb = (buf ^ 1) * 4096;
      gload16(gA0 + k0 + 32, As + nb + wslot);
      gload16(gA0 + (size_t)64 * 768 + k0 + 32, As + nb + wslot + 2048);
      gload16(gB0 + k0 + 32, Bs + nb + wslot);
      gload16(gB0 + (size_t)64 * 768 + k0 + 32, Bs + nb + wslot + 2048);
      asm volatile("s_waitcnt vmcnt(4)" ::: "memory");  // cur tile's 4 done
    } else {
      asm volatile("s_waitcnt vmcnt(0)" ::: "memory");  // last tile: drain
    }
    __builtin_amdgcn_s_barrier();   // all threads' cur-tile loads landed

    const unsigned short* fA = As + buf * 4096 + (size_t)(wm * 64 + lr) * 32 + lg * 8;
    const unsigned short* fB = Bs + buf * 4096 + (size_t)(wn * 64 + lr) * 32 + lg * 8;
    short8 af[4], bf[4];
#pragma unroll
    for (int m = 0; m < 4; m++) af[m] = *(const short8*)(fA + m * 16 * 32);
#pragma unroll
    for (int n = 0; n < 4; n++) bf[n] = *(const short8*)(fB + n * 16 * 32);
    __builtin_amdgcn_s_setprio(1);
#pragma unroll
    for (int m = 0; m < 4; m++)
#pragma unroll
      for (int n = 0; n < 4; n++)
        acc[m][n] = __builtin_amdgcn_mfma_f32_16x16x32_bf16(af[m], bf[n], acc[m][n], 0, 0, 0);
    __builtin_amdgcn_s_setprio(0);
    __builtin_amdgcn_s_barrier();   // release read buffer before restage
    buf ^= 1;
  }
}

// ---------------------------------------------------------------- QKV gemm
// z=0: Q (scaled by 0.125*log2e for exp2-domain softmax), z=1: K, z=2: V
// written DIRECTLY transposed to Vt[B,H,D,S] (fused transpose).
__global__ __launch_bounds__(256) void qkv_gemm(
    const unsigned short* __restrict__ Xq, const unsigned short* __restrict__ Xk,
    const unsigned short* __restrict__ Xv,
    const unsigned short* __restrict__ Wq, const unsigned short* __restrict__ Wk,
    const unsigned short* __restrict__ Wv,
    const float* __restrict__ bq, const float* __restrict__ bk,
    const float* __restrict__ bv,
    unsigned short* __restrict__ Oq, unsigned short* __restrict__ Ok,
    unsigned short* __restrict__ Vt) {
  __shared__ unsigned short As[2 * 4096], Bs[2 * 4096];
  const int z = blockIdx.z;
  const unsigned short* A  = (z == 0) ? Xq : (z == 1) ? Xk : Xv;
  const unsigned short* Bt = (z == 0) ? Wq : (z == 1) ? Wk : Wv;
  const float* bias        = (z == 0) ? bq : (z == 1) ? bk : bv;
  // 0.125 * log2(e): QK^T scores land in log2 domain -> exp2 softmax
  const float scale = (z == 0) ? 0.125f * 1.44269504f : 1.0f;

  const int m0 = blockIdx.x * 128, n0 = blockIdx.y * 128;
  f32x4 acc[4][4] = {};
  gemm_core(A, Bt, As, Bs, m0, n0, threadIdx.x, acc);

  const int tid = threadIdx.x, w = tid >> 6, l = tid & 63;
  const int wm = w >> 1, wn = w & 1, lr = l & 15, lg = l >> 4;
  if (z == 2) {
    // fused V transpose: write Vt[((b*NH+h)*DH + d)*S + s]
#pragma unroll
    for (int n = 0; n < 4; n++) {
      const int ng = n0 + wn * 64 + n * 16 + lr;
      const float bvv = bias[ng];
      const int h = ng >> 6, d = ng & 63;
#pragma unroll
      for (int m = 0; m < 4; m++) {
#pragma unroll
        for (int r = 0; r < 4; r++) {
          const int mg = m0 + wm * 64 + m * 16 + lg * 4 + r;
          const int b = mg >> 11, s = mg & 2047;
          Vt[((size_t)(b * NH_ + h) * DH_ + d) * S_ + s] = f2bf(acc[m][n][r] + bvv);
        }
      }
    }
  } else {
    unsigned short* O = (z == 0) ? Oq : Ok;
#pragma unroll
    for (int n = 0; n < 4; n++) {
      const int ng = n0 + wn * 64 + n * 16 + lr;
      const float bvv = bias[ng];
      const int h = ng >> 6, d = ng & 63;
#pragma unroll
      for (int m = 0; m < 4; m++) {
#pragma unroll
        for (int r = 0; r < 4; r++) {
          const int mg = m0 + wm * 64 + m * 16 + lg * 4 + r;
          const int b = mg >> 11, s = mg & 2047;
          O[((size_t)(b * NH_ + h) * S_ + s) * DH_ + d] = f2bf((acc[m][n][r] + bvv) * scale);
        }
      }
    }
  }
}

// ---------------------------------------------------------------- out gemm
__global__ __launch_bounds__(256) void out_gemm(
    const unsigned short* __restrict__ A, const unsigned short* __restrict__ Bt,
    const float* __restrict__ bias, float* __restrict__ out) {
  __shared__ unsigned short As[2 * 4096], Bs[2 * 4096];
  const int m0 = blockIdx.x * 128, n0 = blockIdx.y * 128;
  f32x4 acc[4][4] = {};
  gemm_core(A, Bt, As, Bs, m0, n0, threadIdx.x, acc);

  const int tid = threadIdx.x, w = tid >> 6, l = tid & 63;
  const int wm = w >> 1, wn = w & 1, lr = l & 15, lg = l >> 4;
#pragma unroll
  for (int n = 0; n < 4; n++) {
    const int ng = n0 + wn * 64 + n * 16 + lr;
    const float bvv = bias[ng];
#pragma unroll
    for (int m = 0; m < 4; m++) {
#pragma unroll
      for (int r = 0; r < 4; r++) {
        const int mg = m0 + wm * 64 + m * 16 + lg * 4 + r;
        out[(size_t)mg * 768 + ng] = acc[m][n][r] + bvv;
      }
    }
  }
}

// ---------------------------------------------------------------- attention
// Swapped-QK^T flash attn, LDS-pipelined (T3 minimum 2-phase), exp2-domain
// softmax (log2e folded into Q scale; hardware v_exp_f32). 4 waves x 32 q,
// grid 768 (XCD-swizzled, 6 bh/XCD). KV tile = 64 keys double-buffered via
// global_load_lds with pre-swizzled SOURCE (rule #21); reads XOR-deswizzle.
// Ps row stride = 72 shorts: payload is 64 keys (64 shorts) + 8 pad.
__global__ __launch_bounds__(256) void attn_kernel(
    const unsigned short* __restrict__ Qp, const unsigned short* __restrict__ Kp,
    const unsigned short* __restrict__ Vt, const float* __restrict__ maskadd,
    unsigned short* __restrict__ Ctx) {
  __shared__ unsigned short KsA[4096], KsB[4096];  // [key][d] swizzled, 8KB each
  __shared__ unsigned short VsA[4096], VsB[4096];  // [d][key] swizzled
  __shared__ unsigned short Ps[4][16][72];         // per-wave P relayout buffer

  // XCD swizzle: xcd = id & 7 (hw maps blockIdx%8 -> XCD); 6 bh per XCD
  const int id = blockIdx.x;               // 0..767
  const int xcd = id & 7, slot = id >> 3;  // 96 slots
  const int bh = xcd + 8 * (slot >> 4);    // 48 bh
  const int qt = slot & 15;                // 16 q-tiles of 128
  const int b = bh / NH_, h = bh % NH_;
  const int tid = threadIdx.x, w = tid >> 6, l = tid & 63;
  const int lr = l & 15, lg = l >> 4;
  const int rsw = lr & 7;
  const int qw = qt * 128 + w * 32;

  // Q fragments (B-operand of S^T): lane lr = q, k-dim d = lg*8 + ks*32
  short8 aq[2][2];
#pragma unroll
  for (int qb = 0; qb < 2; qb++)
#pragma unroll
    for (int ks = 0; ks < 2; ks++)
      aq[qb][ks] = *(const short8*)&Qp[((size_t)bh * S_ + qw + qb * 16 + lr) * DH_ +
                                       lg * 8 + ks * 32];

  // staging addresses: thread covers LDS 16B-units {tid, tid+256};
  // unit u: row=u>>3, c=u&7; source col unit cg = c ^ (row&7) (involution)
  const int r0 = tid >> 3, c0 = tid & 7;
  const int cg = c0 ^ (r0 & 7);
  const unsigned short* Kg0 = Kp + ((size_t)bh * S_ + r0) * DH_ + cg * 8;
  const unsigned short* Kg1 = Kg0 + (size_t)32 * DH_;
  const unsigned short* Vg0 = Vt + ((size_t)bh * DH_ + r0) * S_ + cg * 8;
  const unsigned short* Vg1 = Vg0 + (size_t)32 * S_;
  const int wslot = w * 512;  // wave-uniform LDS offset

  const float* Mb = maskadd + b * S_ + lg * 4;

  float m_run[2], l_run[2];
  f32x4 ctx[2][4] = {};
#pragma unroll
  for (int qb = 0; qb < 2; qb++) { m_run[qb] = -INFINITY; l_run[qb] = 0.f; }

  unsigned short* Pw = &Ps[w][0][0];
  unsigned* Prow = (unsigned*)(Pw + lr * 72);
  const unsigned short* Prd = Pw + lr * 72 + lg * 8;

  unsigned short *Krd = KsA, *Vrd = VsA, *Kwr = KsB, *Vwr = VsB;

  // prologue: stage tile 0
  gload16(Kg0, KsA + wslot);
  gload16(Kg1, KsA + 2048 + wslot);
  gload16(Vg0, VsA + wslot);
  gload16(Vg1, VsA + 2048 + wslot);
  __syncthreads();

  for (int kt = 0; kt < S_ / 64; kt++) {
    // ---- stage NEXT tile into write buffer (async, drains at end barrier)
    if (kt + 1 < S_ / 64) {
      const size_t ko = (size_t)(kt + 1) * 64 * DH_;
      const int vo = (kt + 1) * 64;
      gload16(Kg0 + ko, Kwr + wslot);
      gload16(Kg1 + ko, Kwr + 2048 + wslot);
      gload16(Vg0 + vo, Vwr + wslot);
      gload16(Vg1 + vo, Vwr + 2048 + wslot);
    }

    // ---- mask addend (L2-hot)
    const int kv0 = kt * 64;
    f32x4 mk[4];
#pragma unroll
    for (int t = 0; t < 4; t++) mk[t] = *(const f32x4*)(Mb + kv0 + 16 * t);

    // ---- S^T = K.Q from LDS (swizzled reads), both q sub-blocks share kf
    f32x4 sacc[2][4] = {};
    __builtin_amdgcn_s_setprio(1);
#pragma unroll
    for (int t = 0; t < 4; t++) {
      const int row = 16 * t + lr;
      short8 kf0 = *(const short8*)&Krd[row * 64 + ((lg) ^ rsw) * 8];
      short8 kf1 = *(const short8*)&Krd[row * 64 + ((lg + 4) ^ rsw) * 8];
      sacc[0][t] = __builtin_amdgcn_mfma_f32_16x16x32_bf16(kf0, aq[0][0], sacc[0][t], 0, 0, 0);
      sacc[0][t] = __builtin_amdgcn_mfma_f32_16x16x32_bf16(kf1, aq[0][1], sacc[0][t], 0, 0, 0);
      sacc[1][t] = __builtin_amdgcn_mfma_f32_16x16x32_bf16(kf0, aq[1][0], sacc[1][t], 0, 0, 0);
      sacc[1][t] = __builtin_amdgcn_mfma_f32_16x16x32_bf16(kf1, aq[1][1], sacc[1][t], 0, 0, 0);
    }
    __builtin_amdgcn_s_setprio(0);

    // ---- softmax (exp2 domain) per q sub-block; P -> per-wave LDS -> pa regs
    short8 pa[2][2];
#pragma unroll
    for (int qb = 0; qb < 2; qb++) {
#pragma unroll
      for (int t = 0; t < 4; t++)
#pragma unroll
        for (int r = 0; r < 4; r++) sacc[qb][t][r] += mk[t][r];

      // max-reduce via v_max3-friendly triples (16 vals -> 8 insts)
      float t0 = fmaxf(fmaxf(sacc[qb][0][0], sacc[qb][0][1]), sacc[qb][0][2]);
      float t1 = fmaxf(fmaxf(sacc[qb][0][3], sacc[qb][1][0]), sacc[qb][1][1]);
      float t2 = fmaxf(fmaxf(sacc[qb][1][2], sacc[qb][1][3]), sacc[qb][2][0]);
      float t3 = fmaxf(fmaxf(sacc[qb][2][1], sacc[qb][2][2]), sacc[qb][2][3]);
      float t4 = fmaxf(fmaxf(sacc[qb][3][0], sacc[qb][3][1]), sacc[qb][3][2]);
      float mx = fmaxf(fmaxf(fmaxf(t0, t1), fmaxf(t2, t3)),
                       fmaxf(t4, sacc[qb][3][3]));
      mx = fmaxf(mx, __shfl_xor(mx, 16));
      mx = fmaxf(mx, __shfl_xor(mx, 32));

      // defer-max (log2 domain: 8 nats ~ 11.5 bits)
      if (!__all(mx <= m_run[qb] + 11.5f)) {
        const float nm = fmaxf(m_run[qb], mx);
        const float al = fexp2(m_run[qb] - nm);
        m_run[qb] = nm;
        l_run[qb] *= al;
        float av[4];
#pragma unroll
        for (int r = 0; r < 4; r++) av[r] = __shfl(al, lg * 4 + r, 16);
#pragma unroll
        for (int dt = 0; dt < 4; dt++)
#pragma unroll
          for (int r = 0; r < 4; r++) ctx[qb][dt][r] *= av[r];
      }

      float ts = 0.f;
#pragma unroll
      for (int t = 0; t < 4; t++)
#pragma unroll
        for (int r = 0; r < 4; r++) {
          const float p = fexp2(sacc[qb][t][r] - m_run[qb]);
          sacc[qb][t][r] = p; ts += p;
        }
      ts += __shfl_xor(ts, 16);
      ts += __shfl_xor(ts, 32);
      l_run[qb] += ts;

      // P -> bf16 (cvt_pk) -> per-wave LDS row -> A-fragment regs
#pragma unroll
      for (int t = 0; t < 4; t++) {
        u32x2 c;
        c.x = cvtpk_bf16(sacc[qb][t][0], sacc[qb][t][1]);
        c.y = cvtpk_bf16(sacc[qb][t][2], sacc[qb][t][3]);
        *(u32x2*)(Prow + 8 * t + lg * 2) = c;
      }
      pa[qb][0] = *(const short8*)(Prd);
      pa[qb][1] = *(const short8*)(Prd + 32);
    }

    // ---- PV: vf read once, shared by both q sub-blocks
    __builtin_amdgcn_s_setprio(1);
#pragma unroll
    for (int dt = 0; dt < 4; dt++) {
      const int row = 16 * dt + lr;
      short8 vf0 = *(const short8*)&Vrd[row * 64 + ((lg) ^ rsw) * 8];
      short8 vf1 = *(const short8*)&Vrd[row * 64 + ((lg + 4) ^ rsw) * 8];
      ctx[0][dt] = __builtin_amdgcn_mfma_f32_16x16x32_bf16(pa[0][0], vf0, ctx[0][dt], 0, 0, 0);
      ctx[0][dt] = __builtin_amdgcn_mfma_f32_16x16x32_bf16(pa[0][1], vf1, ctx[0][dt], 0, 0, 0);
      ctx[1][dt] = __builtin_amdgcn_mfma_f32_16x16x32_bf16(pa[1][0], vf0, ctx[1][dt], 0, 0, 0);
      ctx[1][dt] = __builtin_amdgcn_mfma_f32_16x16x32_bf16(pa[1][1], vf1, ctx[1][dt], 0, 0, 0);
    }
    __builtin_amdgcn_s_setprio(0);

    // ---- single barrier per tile: drains stage (vmcnt0) + protects buffers
    __syncthreads();
    unsigned short* t0p = Krd; Krd = Kwr; Kwr = t0p;
    unsigned short* t1p = Vrd; Vrd = Vwr; Vwr = t1p;
  }

  // ---- epilogue: normalize, write bf16 ctx
#pragma unroll
  for (int qb = 0; qb < 2; qb++) {
    const float linv = 1.f / l_run[qb];
    float iv[4];
#pragma unroll
    for (int r = 0; r < 4; r++) iv[r] = __shfl(linv, lg * 4 + r, 16);
#pragma unroll
    for (int r = 0; r < 4; r++) {
      const int qg = qw + qb * 16 + lg * 4 + r;
#pragma unroll
      for (int dt = 0; dt < 4; dt++) {
        Ctx[((size_t)b * S_ + qg) * D_ + h * DH_ + dt * 16 + lr] =
            f2bf(ctx[qb][dt][r] * iv[r]);
      }
    }
  }
}

// ---------------------------------------------------------------- launcher
extern "C" void kernel_launch(void* const* d_in, const int* in_sizes, int n_in,
                              void* d_out, int out_size, void* d_ws, size_t ws_size,
                              hipStream_t stream) {
  const float* q   = (const float*)d_in[0];
  const float* k   = (const float*)d_in[1];
  const float* v   = (const float*)d_in[2];
  const int* mask  = (const int*)d_in[3];
  const float* q_w = (const float*)d_in[4];
  const float* q_b = (const float*)d_in[5];
  const float* k_w = (const float*)d_in[6];
  const float* k_b = (const float*)d_in[7];
  const float* v_w = (const float*)d_in[8];
  const float* v_b = (const float*)d_in[9];
  const float* o_w = (const float*)d_in[10];
  const float* o_b = (const float*)d_in[11];
  float* out = (float*)d_out;

  unsigned short* ws = (unsigned short*)d_ws;
  unsigned short* Xq = ws;
  unsigned short* Xk = Xq + NX;
  unsigned short* Xv = Xk + NX;
  unsigned short* Wq = Xv + NX;   // Wq..Wo contiguous (convert writes combined)
  unsigned short* Wk = Wq + NW;
  unsigned short* Wv = Wk + NW;
  unsigned short* Wo = Wv + NW;
  unsigned short* Qp = Wo + NW;
  unsigned short* Kp = Qp + NX;
  unsigned short* Vt = Kp + NX;   // V written transposed directly by qkv_gemm
  float* Ma = (float*)(Vt + NX);  // mask addend table, 4x2048 f32
  unsigned short* Ctx = Xq;       // alias: Xq dead after its GEMM

  convert_kernel<<<dim3(20744), dim3(256), 0, stream>>>(
      q, k, v, q_w, k_w, v_w, o_w, mask, Xq, Xk, Xv, Wq, Ma);

  qkv_gemm<<<dim3(64, 6, 3), dim3(256), 0, stream>>>(
      Xq, Xk, Xv, Wq, Wk, Wv, q_b, k_b, v_b, Qp, Kp, Vt);

  attn_kernel<<<dim3(768), dim3(256), 0, stream>>>(Qp, Kp, Vt, Ma, Ctx);

  out_gemm<<<dim3(64, 6), dim3(256), 0, stream>>>(Ctx, Wo, o_b, out);
}